// Round 11
// baseline (579.680 us; speedup 1.0000x reference)
//
#include <hip/hip_runtime.h>
#include <math.h>

// CG tensor offsets inside cg buffer (floats)
#define CG110 0
#define CG220 9
#define CG121 34
#define CG211 79
#define CG231 124
#define CG112 229
#define CG132 274
#define CG222 379
#define CGTOT 504

// ---------------- CG coefficient init (device, double precision) ----------------
__device__ double dfact(int n){ double r=1.0; for(int i=2;i<=n;i++) r*=(double)i; return r; }

__device__ double cg_coeff(int j1,int m1,int j2,int m2,int j3,int m3){
  if(m1+m2!=m3) return 0.0;
  int lo = j1>j2 ? j1-j2 : j2-j1;
  if(j3 < lo || j3 > j1+j2) return 0.0;
  double pref = sqrt((double)(2*j3+1)*dfact(j3+j1-j2)*dfact(j3-j1+j2)*dfact(j1+j2-j3)/dfact(j1+j2+j3+1));
  pref *= sqrt(dfact(j3+m3)*dfact(j3-m3)*dfact(j1-m1)*dfact(j1+m1)*dfact(j2-m2)*dfact(j2+m2));
  double s=0.0;
  for(int k=0;k<=j1+j2+j3;k++){
    int d0=j1+j2-j3-k, d1=j1-m1-k, d2=j2+m2-k, d3=j3-j2+m1+k, d4=j3-j1-m2+k;
    if(d0<0||d1<0||d2<0||d3<0||d4<0) continue;
    double term = 1.0/(dfact(k)*dfact(d0)*dfact(d1)*dfact(d2)*dfact(d3)*dfact(d4));
    s += (k&1)? -term : term;
  }
  return pref*s;
}

__device__ void u_elem(int l,int i,int a,double& re,double& im){
  const double s=0.70710678118654752440;
  re=0.0; im=0.0;
  int mi=i-l, ma=a-l;
  if(mi==0){ if(ma==0) re=1.0; }
  else if(mi>0){ if(ma==mi) re=(mi&1)?-s:s; else if(ma==-mi) re=s; }
  else { int m=-mi; if(ma==mi) im=s; else if(ma==-mi) im=(m&1)?s:-s; }
}

__device__ float real_cg_elem(int l1,int l2,int l3,int ii,int jj,int kk){
  double acc=0.0;
  int alist[2]={ii, 2*l1-ii}; int na=(alist[1]==alist[0])?1:2;
  int blist[2]={jj, 2*l2-jj}; int nb=(blist[1]==blist[0])?1:2;
  int clist[2]={kk, 2*l3-kk}; int nc=(clist[1]==clist[0])?1:2;
  for(int ai=0;ai<na;ai++) for(int bi=0;bi<nb;bi++) for(int ci=0;ci<nc;ci++){
    int a=alist[ai], b=blist[bi], c=clist[ci];
    double w = cg_coeff(l1,a-l1,l2,b-l2,l3,c-l3);
    if(w==0.0) continue;
    double u1r,u1i,u2r,u2i,u3r,u3i;
    u_elem(l1,ii,a,u1r,u1i); u_elem(l2,jj,b,u2r,u2i); u_elem(l3,kk,c,u3r,u3i);
    double ar = u1r*u2r - u1i*u2i;
    double aiv= u1r*u2i + u1i*u2r;
    acc += (ar*u3r + aiv*u3i)*w;
  }
  return (float)acc;
}

__global__ void cg_init_kernel(float* __restrict__ cgbuf){
  int tid = blockIdx.x*blockDim.x + threadIdx.x;
  if(tid>=CGTOT) return;
  const int l1s[8]={1,2,1,2,2,1,1,2};
  const int l2s[8]={1,2,2,1,3,1,3,2};
  const int l3s[8]={0,0,1,1,1,2,2,2};
  const int offs[9]={CG110,CG220,CG121,CG211,CG231,CG112,CG132,CG222,CGTOT};
  int t=0;
  for(int u=0;u<8;u++){ if(tid>=offs[u] && tid<offs[u+1]){ t=u; break; } }
  int l1=l1s[t], l2=l2s[t], l3=l3s[t];
  int rem = tid - offs[t];
  int d3=2*l3+1, d2=2*l2+1;
  int k = rem % d3; int j = (rem/d3)%d2; int i = rem/(d3*d2);
  cgbuf[tid] = real_cg_elem(l1,l2,l3,i,j,k);
}

// per-edge TP weight entry
__device__ __forceinline__ float w_entry(int idx, const float* sh, const float* cgs){
  float v = 0.f;
  if (idx < 3){
    int i=idx;
    #pragma unroll
    for(int j=0;j<3;j++) v += sh[j]*cgs[CG110+i*3+j];
  } else if (idx < 8){
    int i=idx-3;
    #pragma unroll
    for(int j=0;j<5;j++) v += sh[3+j]*cgs[CG220+i*5+j];
  } else if (idx < 17){
    int r=idx-8; int i=r/3, c=r-3*i;
    #pragma unroll
    for(int j=0;j<5;j++) v += sh[3+j]*cgs[CG121+(i*5+j)*3+c];
  } else if (idx < 32){
    int r=idx-17; int i=r/3, c=r-3*i;
    #pragma unroll
    for(int j=0;j<3;j++) v += sh[j]*cgs[CG211+(i*3+j)*3+c];
  } else if (idx < 47){
    int r=idx-32; int i=r/3, c=r-3*i;
    #pragma unroll
    for(int j=0;j<7;j++) v += sh[8+j]*cgs[CG231+(i*7+j)*3+c];
  } else if (idx < 62){
    int r=idx-47; int i=r/5, c=r-5*i;
    #pragma unroll
    for(int j=0;j<3;j++) v += sh[j]*cgs[CG112+(i*3+j)*5+c];
  } else if (idx < 77){
    int r=idx-62; int i=r/5, c=r-5*i;
    #pragma unroll
    for(int j=0;j<7;j++) v += sh[8+j]*cgs[CG132+(i*7+j)*5+c];
  } else if (idx < 102){
    int r=idx-77; int i=r/5, c=r-5*i;
    #pragma unroll
    for(int j=0;j<5;j++) v += sh[3+j]*cgs[CG222+(i*5+j)*5+c];
  }
  return v;
}

// g_packed layout (per node, 576): [0,64) l0 f ; [64,256) l1 c*64+f ; [256,576) l2 c*64+f

// ---------------- node linears (fallback, species-dependent) ----------------
__global__ __launch_bounds__(256) void node_linear_kernel(
    const float* __restrict__ node_feats, const int* __restrict__ specie,
    const float* __restrict__ Wsc0, const float* __restrict__ Wsc1, const float* __restrict__ Wsc2,
    const float* __restrict__ Wu0,  const float* __restrict__ Wu1,  const float* __restrict__ Wu2,
    float* __restrict__ g_packed, float* __restrict__ sc_packed, int N)
{
  __shared__ float feat[576];
  int n = blockIdx.x; if(n>=N) return;
  const float4* src = (const float4*)(node_feats + (size_t)n*576);
  float4* fd = (float4*)feat;
  for(int i=threadIdx.x;i<144;i+=256) fd[i]=src[i];
  __syncthreads();
  int sp = specie[n];
  const float inv_f = 0.125f;
  for(int o=threadIdx.x; o<1152; o+=256){
    int isSc = (o>=576);
    int p = o - (isSc?576:0);
    float acc=0.f;
    if(p<64){
      const float* W = isSc ? (Wsc0 + (size_t)sp*4096) : Wu0;
      #pragma unroll 8
      for(int f=0; f<64; f++) acc += feat[f]*W[f*64+p];
    } else if(p<256){
      int q=p-64; int f,c;
      if (isSc){ f=q/3; c=q-3*f; } else { c=q>>6; f=q&63; }
      const float* W = isSc ? (Wsc1 + (size_t)sp*4096) : Wu1;
      #pragma unroll 8
      for(int fp=0; fp<64; fp++) acc += feat[64+3*fp+c]*W[fp*64+f];
    } else {
      int q=p-256; int f,c;
      if (isSc){ f=q/5; c=q-5*f; } else { c=q>>6; f=q&63; }
      const float* W = isSc ? (Wsc2 + (size_t)sp*4096) : Wu2;
      #pragma unroll 8
      for(int fp=0; fp<64; fp++) acc += feat[256+5*fp+c]*W[fp*64+f];
    }
    float* dst = isSc ? sc_packed : g_packed;
    dst[(size_t)n*576 + p] = acc*inv_f;
  }
}

// ---------------- node linears as tiled GEMM (n_species==1 fast path) ----------------
__global__ __launch_bounds__(256) void node_gemm_kernel(
  const float* __restrict__ node_feats,
  const float* __restrict__ Wsc0, const float* __restrict__ Wsc1, const float* __restrict__ Wsc2,
  const float* __restrict__ Wu0,  const float* __restrict__ Wu1,  const float* __restrict__ Wu2,
  float* __restrict__ g_packed, float* __restrict__ sc_packed, int N)
{
  __shared__ float As[64][17];
  __shared__ float Bs[16][64];
  int tid = threadIdx.x;
  int tx = tid & 15, ty = tid >> 4;
  int s = blockIdx.y;
  int n0 = blockIdx.x*64;

  int sub = s % 9;
  int isSc = (s >= 9);
  int abase, astride;
  const float* W;
  if (sub == 0){ abase = 0; astride = 1; W = isSc? Wsc0 : Wu0; }
  else if (sub < 4){ int c = sub-1; abase = 64+c; astride = 3; W = isSc? Wsc1 : Wu1; }
  else { int c = sub-4; abase = 256+c; astride = 5; W = isSc? Wsc2 : Wu2; }
  int obase, ostride;
  if (isSc){ obase = abase; ostride = astride; }
  else {
    if (sub==0){ obase=0; ostride=1; }
    else if (sub<4){ obase = 64+64*(sub-1); ostride=1; }
    else { obase = 256+64*(sub-4); ostride=1; }
  }
  float* dst = isSc ? sc_packed : g_packed;

  float acc[4][4];
  #pragma unroll
  for(int i=0;i<4;i++)
    #pragma unroll
    for(int j=0;j<4;j++) acc[i][j]=0.f;

  for (int k0=0; k0<64; k0+=16){
    #pragma unroll
    for (int l=0;l<4;l++){
      int idx = tid + l*256;
      int row = idx>>4, kk = idx&15;
      int n = n0+row;
      As[row][kk] = (n<N)? node_feats[(size_t)n*576 + abase + astride*(k0+kk)] : 0.f;
    }
    #pragma unroll
    for (int l=0;l<4;l++){
      int idx = tid + l*256;
      int kk = idx>>6, j = idx&63;
      Bs[kk][j] = W[(k0+kk)*64 + j];
    }
    __syncthreads();
    #pragma unroll
    for (int kk=0; kk<16; kk++){
      float av[4];
      #pragma unroll
      for(int i=0;i<4;i++) av[i] = As[ty*4+i][kk];
      float4 bv = *(const float4*)&Bs[kk][tx*4];
      #pragma unroll
      for(int i=0;i<4;i++){
        acc[i][0] += av[i]*bv.x; acc[i][1] += av[i]*bv.y;
        acc[i][2] += av[i]*bv.z; acc[i][3] += av[i]*bv.w;
      }
    }
    __syncthreads();
  }
  const float scale = 0.125f;  // 1/sqrt(64)
  #pragma unroll
  for(int i=0;i<4;i++){
    int n = n0 + ty*4+i;
    if (n>=N) continue;
    #pragma unroll
    for(int j=0;j<4;j++){
      int f = tx*4+j;
      dst[(size_t)n*576 + obase + ostride*f] = acc[i][j]*scale;
    }
  }
}

// ---------------- CSR build ----------------
__global__ void count_kernel(const int* __restrict__ recv, int* __restrict__ counts, int E){
  int e = blockIdx.x*256 + threadIdx.x;
  if(e<E) atomicAdd(&counts[recv[e]],1);
}

__global__ __launch_bounds__(1024) void scan_kernel(const int* __restrict__ counts,
                                                    int* __restrict__ offsets,
                                                    int* __restrict__ cursor, int n){
  __shared__ int tmp[1024];
  int tid = threadIdx.x;
  int per = (n + 1023)/1024;
  int base = tid*per;
  int s = 0;
  for(int i=0;i<per;i++){ int idx=base+i; if(idx<n) s += counts[idx]; }
  tmp[tid]=s; __syncthreads();
  for(int off=1; off<1024; off<<=1){
    int v = (tid>=off)? tmp[tid-off] : 0;
    __syncthreads();
    tmp[tid]+=v;
    __syncthreads();
  }
  int run = (tid==0)? 0 : tmp[tid-1];
  for(int i=0;i<per;i++){
    int idx=base+i;
    if(idx<n){ offsets[idx]=run; cursor[idx]=run; run += counts[idx]; }
  }
  if(tid==1023) offsets[n]=tmp[1023];
}

__global__ void scatter_kernel(const int* __restrict__ recv, int* __restrict__ cursor,
                               int* __restrict__ edge_list, int E){
  int e = blockIdx.x*256 + threadIdx.x;
  if(e<E){ int pos=atomicAdd(&cursor[recv[e]],1); edge_list[pos]=e; }
}

// ---------------- fused geometry + radial MLP per edge (pos-indexed) ----------------
__global__ __launch_bounds__(256) void geomh_kernel(
  const float* __restrict__ vectors, const int* __restrict__ edge_list,
  const int* __restrict__ senders,
  const float* __restrict__ Wm1, const float* __restrict__ Wm2,
  float* __restrict__ shbuf, float* __restrict__ h2buf, int* __restrict__ spos, int E)
{
  int pos = blockIdx.x*256 + threadIdx.x;
  bool valid = pos < E;
  int pp = valid ? pos : (E-1);
  int e = edge_list[pp];
  if (valid) spos[pos] = senders[e];
  float vx=vectors[e*3], vy=vectors[e*3+1], vz=vectors[e*3+2];
  float x2 = vx*vx+vy*vy+vz*vz;
  float x  = sqrtf(fmaxf(x2, 1e-12f));
  float inv= 1.f/x;
  float ux=vx*inv, uy=vy*inv, uz=vz*inv;
  float env = 0.f;
  if(x<1.f){
    float x3=x*x*x; float x6=x3*x3; float x7=x6*x; float x8=x7*x;
    env = 1.f-28.f*x6+48.f*x7-21.f*x8;
  }
  float rad[8];
  #pragma unroll
  for(int nn=1;nn<=8;nn++)
    rad[nn-1] = 1.4142135623730951f * sinf(3.14159265358979323846f*(float)nn*x)*inv*env;
  {
    float sh[16];
    const float s3=1.7320508075688772f;
    sh[0]=s3*uy; sh[1]=s3*uz; sh[2]=s3*ux;
    const float s15=3.872983346207417f, s5=2.23606797749979f;
    sh[3]=s15*ux*uy; sh[4]=s15*uy*uz;
    sh[5]=0.5f*s5*(3.f*uz*uz-1.f);
    sh[6]=s15*ux*uz; sh[7]=0.5f*s15*(ux*ux-uy*uy);
    const float c35=2.091650066335189f, c105=10.246950765959598f;
    const float c21=1.620185174601965f, c7=1.3228756555322954f;
    sh[8] =c35*uy*(3.f*ux*ux-uy*uy);
    sh[9] =c105*ux*uy*uz;
    sh[10]=c21*uy*(5.f*uz*uz-1.f);
    sh[11]=c7*uz*(5.f*uz*uz-3.f);
    sh[12]=c21*ux*(5.f*uz*uz-1.f);
    sh[13]=0.5f*c105*uz*(ux*ux-uy*uy);
    sh[14]=c35*ux*(ux*ux-3.f*uy*uy);
    sh[15]=0.f;
    if (valid){
      float* sb = shbuf + (size_t)pos*16;
      #pragma unroll
      for(int k=0;k<16;k++) sb[k]=sh[k];
    }
  }
  float h2a[64];
  #pragma unroll
  for(int j=0;j<64;j++) h2a[j]=0.f;
  for(int i=0;i<64;i++){
    float a=0.f;
    #pragma unroll
    for(int r=0;r<8;r++) a += rad[r]*Wm1[r*64+i];
    a *= 0.3535533905932738f;           // 1/sqrt(8)
    float h1 = a/(1.f+expf(-a));
    const float* wrow = Wm2 + i*64;
    #pragma unroll
    for(int j=0;j<64;j++) h2a[j] += h1*wrow[j];
  }
  if (valid){
    #pragma unroll
    for(int j=0;j<64;j++){
      float b = h2a[j]*0.125f;          // 1/sqrt(64)
      h2buf[(size_t)j*E + pos] = b/(1.f+expf(-b));
    }
  }
}

// ---------------- mix = h2 @ Wm3 /8  (128x64 tiles, 8x4/thread, fp32 row-major out) ----------------
__global__ __launch_bounds__(256) void mix_gemm_kernel(
  const float* __restrict__ h2buf, const float* __restrict__ Wm3,
  float* __restrict__ mixbuf, int posLo, int cnt, int E)
{
  __shared__ float As[128][17];
  __shared__ float Bs[16][64];
  int tid=threadIdx.x; int tx=tid&15, ty=tid>>4;
  int r0 = blockIdx.x*128;
  int c0 = blockIdx.y*64;          // column tile over 832 (13 tiles)
  float acc[8][4];
  #pragma unroll
  for(int i=0;i<8;i++)
    #pragma unroll
    for(int j=0;j<4;j++) acc[i][j]=0.f;
  for(int k0=0;k0<64;k0+=16){
    // stage A: 128x16 = 2048 elems, 8 per thread; coalesced over pos (row = contiguous)
    #pragma unroll
    for(int l=0;l<8;l++){
      int idx=tid+l*256; int kk=idx>>7, row=idx&127;
      int r=r0+row;
      As[row][kk] = (r<cnt)? h2buf[(size_t)(k0+kk)*E + posLo + r] : 0.f;
    }
    #pragma unroll
    for(int l=0;l<4;l++){
      int idx=tid+l*256; int kk=idx>>6, j=idx&63;
      Bs[kk][j] = Wm3[(size_t)(k0+kk)*832 + c0 + j];
    }
    __syncthreads();
    #pragma unroll
    for(int kk=0;kk<16;kk++){
      float av[8];
      #pragma unroll
      for(int i=0;i<8;i++) av[i]=As[ty*8+i][kk];
      float4 bv = *(const float4*)&Bs[kk][tx*4];
      #pragma unroll
      for(int i=0;i<8;i++){
        acc[i][0]+=av[i]*bv.x; acc[i][1]+=av[i]*bv.y;
        acc[i][2]+=av[i]*bv.z; acc[i][3]+=av[i]*bv.w;
      }
    }
    __syncthreads();
  }
  #pragma unroll
  for(int i=0;i<8;i++){
    int r=r0+ty*8+i;
    if(r>=cnt) continue;
    float4 o;
    o.x=acc[i][0]*0.125f; o.y=acc[i][1]*0.125f;
    o.z=acc[i][2]*0.125f; o.w=acc[i][3]*0.125f;
    *(float4*)&mixbuf[(size_t)r*832 + c0 + tx*4] = o;
  }
}

// ---------------- fused message + segment-sum: one 512-thread block per node ----------------
// a_packed row (2752): [0,192) m0 ; [192,1152) m1 c*320+part*64+f ; [1152,2752) m2 c*320+part*64+f
__global__ __launch_bounds__(512) void node_accum_kernel(
  const float* __restrict__ g_packed, const int* __restrict__ spos,
  const float* __restrict__ shbuf, const float* __restrict__ cgbuf,
  const float* __restrict__ mixbuf, const int* __restrict__ offsets,
  float* __restrict__ a_packed, int posLo, int posHi, int N)
{
  __shared__ float accs[2752];
  __shared__ float cgs[504];
  __shared__ float sh_l[8][16];
  __shared__ float wt_l[8][104];
  int n = blockIdx.x; if (n>=N) return;
  int tid = threadIdx.x, wave = tid>>6, lane = tid&63;
  int e0 = offsets[n], e1 = offsets[n+1];
  int a0 = e0>posLo? e0:posLo;
  int a1 = e1<posHi? e1:posHi;
  bool first = (posLo==0);
  if (!first && a0>=a1) return;

  for (int i=tid;i<2752;i+=512) accs[i]=0.f;
  for (int i=tid;i<504;i+=512) cgs[i]=cgbuf[i];
  __syncthreads();

  float racc[43];
  #pragma unroll
  for(int k=0;k<43;k++) racc[k]=0.f;

  for (int pos=a0+wave; pos<a1; pos+=8){
    int rp = pos - posLo;
    if (lane<16) sh_l[wave][lane] = shbuf[(size_t)pos*16 + lane];
    const float* shv = sh_l[wave];
    wt_l[wave][lane] = w_entry(lane, shv, cgs);
    if (lane<40) wt_l[wave][64+lane] = w_entry(64+lane, shv, cgs);
    const float* W = wt_l[wave];
    const float* g = g_packed + (size_t)spos[pos]*576;
    const float* mx = mixbuf + (size_t)rp*832;
    float s0  = g[lane];
    float s10 = g[64+lane],  s11 = g[128+lane], s12 = g[192+lane];
    float s20 = g[256+lane], s21 = g[320+lane], s22 = g[384+lane],
          s23 = g[448+lane], s24 = g[512+lane];
    // m0 (parts 0,1,2)
    racc[0] += s0*mx[lane];
    racc[1] += (s10*W[0]+s11*W[1]+s12*W[2])*mx[64+lane];
    racc[2] += (s20*W[3]+s21*W[4]+s22*W[5]+s23*W[6]+s24*W[7])*mx[128+lane];
    // m1 (parts 3..7)
    {
      float m0_=mx[192+lane], m1_=mx[256+lane], m2_=mx[320+lane],
            m3_=mx[384+lane], m4_=mx[448+lane];
      float p1v[3]={s10,s11,s12};
      #pragma unroll
      for(int c=0;c<3;c++){
        float v2 = s10*W[8+c]+s11*W[11+c]+s12*W[14+c];
        float v3 = s20*W[17+c]+s21*W[20+c]+s22*W[23+c]+s23*W[26+c]+s24*W[29+c];
        float v4 = s20*W[32+c]+s21*W[35+c]+s22*W[38+c]+s23*W[41+c]+s24*W[44+c];
        racc[3+c*5+0] += p1v[c]*m0_;
        racc[3+c*5+1] += s0*shv[c]*m1_;
        racc[3+c*5+2] += v2*m2_;
        racc[3+c*5+3] += v3*m3_;
        racc[3+c*5+4] += v4*m4_;
      }
    }
    // m2 (parts 8..12)
    {
      float n0_=mx[512+lane], n1_=mx[576+lane], n2_=mx[640+lane],
            n3_=mx[704+lane], n4_=mx[768+lane];
      float p2v[5]={s20,s21,s22,s23,s24};
      #pragma unroll
      for(int c=0;c<5;c++){
        float v2 = s10*W[47+c]+s11*W[52+c]+s12*W[57+c];
        float v3 = s10*W[62+c]+s11*W[67+c]+s12*W[72+c];
        float v4 = s20*W[77+c]+s21*W[82+c]+s22*W[87+c]+s23*W[92+c]+s24*W[97+c];
        racc[18+c*5+0] += p2v[c]*n0_;
        racc[18+c*5+1] += s0*shv[3+c]*n1_;
        racc[18+c*5+2] += v2*n2_;
        racc[18+c*5+3] += v3*n3_;
        racc[18+c*5+4] += v4*n4_;
      }
    }
  }
  __syncthreads();
  // cross-wave merge (8 phases)
  for (int w=0; w<8; w++){
    if (wave==w){
      accs[lane]     += racc[0];
      accs[64+lane]  += racc[1];
      accs[128+lane] += racc[2];
      #pragma unroll
      for(int c=0;c<3;c++)
        #pragma unroll
        for(int p=0;p<5;p++)
          accs[192+c*320+p*64+lane] += racc[3+c*5+p];
      #pragma unroll
      for(int c=0;c<5;c++)
        #pragma unroll
        for(int p=0;p<5;p++)
          accs[1152+c*320+p*64+lane] += racc[18+c*5+p];
    }
    __syncthreads();
  }
  if (first){
    for (int i=tid;i<2752;i+=512) a_packed[(size_t)n*2752+i] = accs[i];
  } else {
    for (int i=tid;i<2752;i+=512) a_packed[(size_t)n*2752+i] += accs[i];
  }
}

// ---------------- output GEMM into dbuf (704/node, comp-major d1/d2), 32-row tiles ----------------
__global__ __launch_bounds__(256) void out_gemm_kernel(
  const float* __restrict__ A, const float* __restrict__ Wd0,
  const float* __restrict__ Wd1, const float* __restrict__ Wd2,
  float* __restrict__ dbuf, int N)
{
  __shared__ float As[32][17];
  __shared__ float Bs[16][64];
  int tid = threadIdx.x;
  int tx = tid & 15, ty = tid >> 4;
  int s = blockIdx.y;
  int n0 = blockIdx.x*32;

  int abase, K, obase, bcol0, bstride;
  const float* W;
  float scale;
  if (s < 3){
    abase = 0; K = 192; W = Wd0; bcol0 = 64*s; bstride = 192;
    obase = 64*s;
    scale = 0.02282177322938192f;      // 1/sqrt(10*192)
  } else if (s < 6){
    int c = s-3;
    abase = 192+320*c; K = 320; W = Wd1; bcol0 = 0; bstride = 64;
    obase = 192+64*c;
    scale = 0.017677669529663688f;     // 1/sqrt(10*320)
  } else {
    int c = s-6;
    abase = 1152+320*c; K = 320; W = Wd2; bcol0 = 0; bstride = 64;
    obase = 384+64*c;
    scale = 0.017677669529663688f;
  }

  float acc[2][4];
  #pragma unroll
  for(int i=0;i<2;i++)
    #pragma unroll
    for(int j=0;j<4;j++) acc[i][j]=0.f;

  for (int k0=0; k0<K; k0+=16){
    #pragma unroll
    for (int l=0;l<2;l++){
      int idx = tid + l*256;
      int row = idx>>4, kk = idx&15;
      int n = n0+row;
      As[row][kk] = (n<N)? A[(size_t)n*2752 + abase + k0+kk] : 0.f;
    }
    #pragma unroll
    for (int l=0;l<4;l++){
      int idx = tid + l*256;
      int kk = idx>>6, j = idx&63;
      Bs[kk][j] = W[(size_t)(k0+kk)*bstride + bcol0 + j];
    }
    __syncthreads();
    #pragma unroll
    for (int kk=0; kk<16; kk++){
      float av[2];
      av[0] = As[ty*2][kk]; av[1] = As[ty*2+1][kk];
      float4 bv = *(const float4*)&Bs[kk][tx*4];
      #pragma unroll
      for(int i=0;i<2;i++){
        acc[i][0] += av[i]*bv.x; acc[i][1] += av[i]*bv.y;
        acc[i][2] += av[i]*bv.z; acc[i][3] += av[i]*bv.w;
      }
    }
    __syncthreads();
  }
  #pragma unroll
  for(int i=0;i<2;i++){
    int n = n0 + ty*2+i;
    if (n>=N) continue;
    #pragma unroll
    for(int j=0;j<4;j++){
      int col = tx*4+j;
      dbuf[(size_t)n*704 + obase + col] = acc[i][j]*scale;
    }
  }
}

// ---------------- epilogue: swish/gates + self connection ----------------
__global__ __launch_bounds__(256) void epilogue_kernel(
  const float* __restrict__ dbuf, const float* __restrict__ sc_packed,
  float* __restrict__ out, int N)
{
  int n = blockIdx.x; if(n>=N) return;
  const float* d = dbuf + (size_t)n*704;
  const float* sc = sc_packed + (size_t)n*576;
  float* o = out + (size_t)n*576;
  for (int p=threadIdx.x; p<576; p+=256){
    float v;
    if (p<64){
      float x = d[p];
      v = x/(1.f+expf(-x)) + sc[p];
    } else if (p<256){
      int r = p-64; int f = r/3, c = r-3*f;
      float g = d[64+f]; g = g/(1.f+expf(-g));
      v = d[192+64*c+f]*g + sc[p];
    } else {
      int r = p-256; int f = r/5, c = r-5*f;
      float g = d[128+f]; g = g/(1.f+expf(-g));
      v = d[384+64*c+f]*g + sc[p];
    }
    o[p] = v;
  }
}

// ---------------- host ----------------
extern "C" void kernel_launch(void* const* d_in, const int* in_sizes, int n_in,
                              void* d_out, int out_size, void* d_ws, size_t ws_size,
                              hipStream_t stream)
{
  const float* vectors    =(const float*)d_in[0];
  const float* node_feats =(const float*)d_in[1];
  const int*   node_specie=(const int*)  d_in[2];
  const int*   senders    =(const int*)  d_in[3];
  const int*   receivers  =(const int*)  d_in[4];
  const float* Wsc0=(const float*)d_in[5];
  const float* Wsc1=(const float*)d_in[6];
  const float* Wsc2=(const float*)d_in[7];
  const float* Wu0 =(const float*)d_in[8];
  const float* Wu1 =(const float*)d_in[9];
  const float* Wu2 =(const float*)d_in[10];
  const float* Wm1 =(const float*)d_in[11];
  const float* Wm2 =(const float*)d_in[12];
  const float* Wm3 =(const float*)d_in[13];
  const float* Wd0 =(const float*)d_in[14];
  const float* Wd1 =(const float*)d_in[15];
  const float* Wd2 =(const float*)d_in[16];
  float* out = (float*)d_out;

  int E = in_sizes[0]/3;
  int N = in_sizes[1]/576;
  int nspec = in_sizes[5]/4096;

  // workspace carve
  float* cgbuf     = (float*)d_ws;                         // 512
  float* g_packed  = cgbuf + 512;                          // N*576
  float* sc_packed = g_packed  + (size_t)N*576;            // N*576
  float* a_packed  = sc_packed + (size_t)N*576;            // N*2752
  float* shbuf     = a_packed + (size_t)N*2752;            // E*16
  float* h2buf     = shbuf + (size_t)E*16;                 // E*64 (transposed [64][E])
  int*   counts    = (int*)(h2buf + (size_t)E*64);         // N
  int*   offsets   = counts + N;                           // N+1
  int*   cursor    = offsets + (N+1);                      // N
  int*   edge_list = cursor + N;                           // E
  int*   spos      = edge_list + E;                        // E
  size_t used_bytes = (size_t)((char*)(spos + E) - (char*)d_ws);
  used_bytes = (used_bytes + 255) & ~(size_t)255;
  size_t avail = (ws_size > used_bytes) ? (ws_size - used_bytes) : 0;
  long long cap = (long long)(avail / (832u*4u));
  if (cap > E) cap = ((long long)E + 7) & ~7ll;     // as many edges per round as fit
  cap = (cap/8)*8;
  if (cap < 8) cap = 8;
  float* mixbuf = (float*)((char*)d_ws + used_bytes);      // cap*832 (row-major fp32)
  float* dbuf   = mixbuf;                                  // reuse after rounds: N*704

  hipMemsetAsync(counts, 0, (size_t)N*sizeof(int), stream);
  cg_init_kernel<<<2,256,0,stream>>>(cgbuf);
  if (nspec == 1){
    dim3 grid((N+63)/64, 18);
    node_gemm_kernel<<<grid,256,0,stream>>>(node_feats,Wsc0,Wsc1,Wsc2,Wu0,Wu1,Wu2,
                                            g_packed,sc_packed,N);
  } else {
    node_linear_kernel<<<N,256,0,stream>>>(node_feats,node_specie,Wsc0,Wsc1,Wsc2,Wu0,Wu1,Wu2,
                                           g_packed,sc_packed,N);
  }
  count_kernel<<<(E+255)/256,256,0,stream>>>(receivers,counts,E);
  scan_kernel<<<1,1024,0,stream>>>(counts,offsets,cursor,N);
  scatter_kernel<<<(E+255)/256,256,0,stream>>>(receivers,cursor,edge_list,E);
  geomh_kernel<<<(E+255)/256,256,0,stream>>>(vectors,edge_list,senders,Wm1,Wm2,
                                             shbuf,h2buf,spos,E);

  for (long long lo=0; lo<E; lo+=cap){
    long long hi = lo + cap; if (hi > E) hi = E;
    int cnt = (int)(hi - lo);
    {
      dim3 grid((cnt+127)/128, 13);
      mix_gemm_kernel<<<grid,256,0,stream>>>(h2buf,Wm3,mixbuf,(int)lo,cnt,E);
    }
    node_accum_kernel<<<N,512,0,stream>>>(g_packed,spos,shbuf,cgbuf,mixbuf,offsets,
                                          a_packed,(int)lo,(int)hi,N);
  }

  {
    dim3 grid((N+31)/32, 11);
    out_gemm_kernel<<<grid,256,0,stream>>>(a_packed,Wd0,Wd1,Wd2,dbuf,N);
  }
  epilogue_kernel<<<N,256,0,stream>>>(dbuf,sc_packed,out,N);
}

// Round 12
// 453.736 us; speedup vs baseline: 1.2776x; 1.2776x over previous
//
#include <hip/hip_runtime.h>
#include <math.h>

// CG tensor offsets inside cg buffer (floats)
#define CG110 0
#define CG220 9
#define CG121 34
#define CG211 79
#define CG231 124
#define CG112 229
#define CG132 274
#define CG222 379
#define CGTOT 504

// ---------------- CG coefficient init (device, double precision) ----------------
__device__ double dfact(int n){ double r=1.0; for(int i=2;i<=n;i++) r*=(double)i; return r; }

__device__ double cg_coeff(int j1,int m1,int j2,int m2,int j3,int m3){
  if(m1+m2!=m3) return 0.0;
  int lo = j1>j2 ? j1-j2 : j2-j1;
  if(j3 < lo || j3 > j1+j2) return 0.0;
  double pref = sqrt((double)(2*j3+1)*dfact(j3+j1-j2)*dfact(j3-j1+j2)*dfact(j1+j2-j3)/dfact(j1+j2+j3+1));
  pref *= sqrt(dfact(j3+m3)*dfact(j3-m3)*dfact(j1-m1)*dfact(j1+m1)*dfact(j2-m2)*dfact(j2+m2));
  double s=0.0;
  for(int k=0;k<=j1+j2+j3;k++){
    int d0=j1+j2-j3-k, d1=j1-m1-k, d2=j2+m2-k, d3=j3-j2+m1+k, d4=j3-j1-m2+k;
    if(d0<0||d1<0||d2<0||d3<0||d4<0) continue;
    double term = 1.0/(dfact(k)*dfact(d0)*dfact(d1)*dfact(d2)*dfact(d3)*dfact(d4));
    s += (k&1)? -term : term;
  }
  return pref*s;
}

__device__ void u_elem(int l,int i,int a,double& re,double& im){
  const double s=0.70710678118654752440;
  re=0.0; im=0.0;
  int mi=i-l, ma=a-l;
  if(mi==0){ if(ma==0) re=1.0; }
  else if(mi>0){ if(ma==mi) re=(mi&1)?-s:s; else if(ma==-mi) re=s; }
  else { int m=-mi; if(ma==mi) im=s; else if(ma==-mi) im=(m&1)?s:-s; }
}

__device__ float real_cg_elem(int l1,int l2,int l3,int ii,int jj,int kk){
  double acc=0.0;
  int alist[2]={ii, 2*l1-ii}; int na=(alist[1]==alist[0])?1:2;
  int blist[2]={jj, 2*l2-jj}; int nb=(blist[1]==blist[0])?1:2;
  int clist[2]={kk, 2*l3-kk}; int nc=(clist[1]==clist[0])?1:2;
  for(int ai=0;ai<na;ai++) for(int bi=0;bi<nb;bi++) for(int ci=0;ci<nc;ci++){
    int a=alist[ai], b=blist[bi], c=clist[ci];
    double w = cg_coeff(l1,a-l1,l2,b-l2,l3,c-l3);
    if(w==0.0) continue;
    double u1r,u1i,u2r,u2i,u3r,u3i;
    u_elem(l1,ii,a,u1r,u1i); u_elem(l2,jj,b,u2r,u2i); u_elem(l3,kk,c,u3r,u3i);
    double ar = u1r*u2r - u1i*u2i;
    double aiv= u1r*u2i + u1i*u2r;
    acc += (ar*u3r + aiv*u3i)*w;
  }
  return (float)acc;
}

__global__ void cg_init_kernel(float* __restrict__ cgbuf){
  int tid = blockIdx.x*blockDim.x + threadIdx.x;
  if(tid>=CGTOT) return;
  const int l1s[8]={1,2,1,2,2,1,1,2};
  const int l2s[8]={1,2,2,1,3,1,3,2};
  const int l3s[8]={0,0,1,1,1,2,2,2};
  const int offs[9]={CG110,CG220,CG121,CG211,CG231,CG112,CG132,CG222,CGTOT};
  int t=0;
  for(int u=0;u<8;u++){ if(tid>=offs[u] && tid<offs[u+1]){ t=u; break; } }
  int l1=l1s[t], l2=l2s[t], l3=l3s[t];
  int rem = tid - offs[t];
  int d3=2*l3+1, d2=2*l2+1;
  int k = rem % d3; int j = (rem/d3)%d2; int i = rem/(d3*d2);
  cgbuf[tid] = real_cg_elem(l1,l2,l3,i,j,k);
}

// per-edge TP weight entry
__device__ __forceinline__ float w_entry(int idx, const float* sh, const float* cgs){
  float v = 0.f;
  if (idx < 3){
    int i=idx;
    #pragma unroll
    for(int j=0;j<3;j++) v += sh[j]*cgs[CG110+i*3+j];
  } else if (idx < 8){
    int i=idx-3;
    #pragma unroll
    for(int j=0;j<5;j++) v += sh[3+j]*cgs[CG220+i*5+j];
  } else if (idx < 17){
    int r=idx-8; int i=r/3, c=r-3*i;
    #pragma unroll
    for(int j=0;j<5;j++) v += sh[3+j]*cgs[CG121+(i*5+j)*3+c];
  } else if (idx < 32){
    int r=idx-17; int i=r/3, c=r-3*i;
    #pragma unroll
    for(int j=0;j<3;j++) v += sh[j]*cgs[CG211+(i*3+j)*3+c];
  } else if (idx < 47){
    int r=idx-32; int i=r/3, c=r-3*i;
    #pragma unroll
    for(int j=0;j<7;j++) v += sh[8+j]*cgs[CG231+(i*7+j)*3+c];
  } else if (idx < 62){
    int r=idx-47; int i=r/5, c=r-5*i;
    #pragma unroll
    for(int j=0;j<3;j++) v += sh[j]*cgs[CG112+(i*3+j)*5+c];
  } else if (idx < 77){
    int r=idx-62; int i=r/5, c=r-5*i;
    #pragma unroll
    for(int j=0;j<7;j++) v += sh[8+j]*cgs[CG132+(i*7+j)*5+c];
  } else if (idx < 102){
    int r=idx-77; int i=r/5, c=r-5*i;
    #pragma unroll
    for(int j=0;j<5;j++) v += sh[3+j]*cgs[CG222+(i*5+j)*5+c];
  }
  return v;
}

// accumulate one edge's messages into racc; mx values scaled by z (0 disables edge)
__device__ __forceinline__ void edge_accum(float* racc, const float* g, const float* W,
                                           const float* shv, const float* mx, float z, int lane)
{
  float s0  = g[lane];
  float s10 = g[64+lane],  s11 = g[128+lane], s12 = g[192+lane];
  float s20 = g[256+lane], s21 = g[320+lane], s22 = g[384+lane],
        s23 = g[448+lane], s24 = g[512+lane];
  racc[0] += s0*(z*mx[lane]);
  racc[1] += (s10*W[0]+s11*W[1]+s12*W[2])*(z*mx[64+lane]);
  racc[2] += (s20*W[3]+s21*W[4]+s22*W[5]+s23*W[6]+s24*W[7])*(z*mx[128+lane]);
  {
    float m0_=z*mx[192+lane], m1_=z*mx[256+lane], m2_=z*mx[320+lane],
          m3_=z*mx[384+lane], m4_=z*mx[448+lane];
    float p1v[3]={s10,s11,s12};
    #pragma unroll
    for(int c=0;c<3;c++){
      float v2 = s10*W[8+c]+s11*W[11+c]+s12*W[14+c];
      float v3 = s20*W[17+c]+s21*W[20+c]+s22*W[23+c]+s23*W[26+c]+s24*W[29+c];
      float v4 = s20*W[32+c]+s21*W[35+c]+s22*W[38+c]+s23*W[41+c]+s24*W[44+c];
      racc[3+c*5+0] += p1v[c]*m0_;
      racc[3+c*5+1] += s0*shv[c]*m1_;
      racc[3+c*5+2] += v2*m2_;
      racc[3+c*5+3] += v3*m3_;
      racc[3+c*5+4] += v4*m4_;
    }
  }
  {
    float n0_=z*mx[512+lane], n1_=z*mx[576+lane], n2_=z*mx[640+lane],
          n3_=z*mx[704+lane], n4_=z*mx[768+lane];
    float p2v[5]={s20,s21,s22,s23,s24};
    #pragma unroll
    for(int c=0;c<5;c++){
      float v2 = s10*W[47+c]+s11*W[52+c]+s12*W[57+c];
      float v3 = s10*W[62+c]+s11*W[67+c]+s12*W[72+c];
      float v4 = s20*W[77+c]+s21*W[82+c]+s22*W[87+c]+s23*W[92+c]+s24*W[97+c];
      racc[18+c*5+0] += p2v[c]*n0_;
      racc[18+c*5+1] += s0*shv[3+c]*n1_;
      racc[18+c*5+2] += v2*n2_;
      racc[18+c*5+3] += v3*n3_;
      racc[18+c*5+4] += v4*n4_;
    }
  }
}

// g_packed layout (per node, 576): [0,64) l0 f ; [64,256) l1 c*64+f ; [256,576) l2 c*64+f

// ---------------- node linears (fallback, species-dependent) ----------------
__global__ __launch_bounds__(256) void node_linear_kernel(
    const float* __restrict__ node_feats, const int* __restrict__ specie,
    const float* __restrict__ Wsc0, const float* __restrict__ Wsc1, const float* __restrict__ Wsc2,
    const float* __restrict__ Wu0,  const float* __restrict__ Wu1,  const float* __restrict__ Wu2,
    float* __restrict__ g_packed, float* __restrict__ sc_packed, int N)
{
  __shared__ float feat[576];
  int n = blockIdx.x; if(n>=N) return;
  const float4* src = (const float4*)(node_feats + (size_t)n*576);
  float4* fd = (float4*)feat;
  for(int i=threadIdx.x;i<144;i+=256) fd[i]=src[i];
  __syncthreads();
  int sp = specie[n];
  const float inv_f = 0.125f;
  for(int o=threadIdx.x; o<1152; o+=256){
    int isSc = (o>=576);
    int p = o - (isSc?576:0);
    float acc=0.f;
    if(p<64){
      const float* W = isSc ? (Wsc0 + (size_t)sp*4096) : Wu0;
      #pragma unroll 8
      for(int f=0; f<64; f++) acc += feat[f]*W[f*64+p];
    } else if(p<256){
      int q=p-64; int f,c;
      if (isSc){ f=q/3; c=q-3*f; } else { c=q>>6; f=q&63; }
      const float* W = isSc ? (Wsc1 + (size_t)sp*4096) : Wu1;
      #pragma unroll 8
      for(int fp=0; fp<64; fp++) acc += feat[64+3*fp+c]*W[fp*64+f];
    } else {
      int q=p-256; int f,c;
      if (isSc){ f=q/5; c=q-5*f; } else { c=q>>6; f=q&63; }
      const float* W = isSc ? (Wsc2 + (size_t)sp*4096) : Wu2;
      #pragma unroll 8
      for(int fp=0; fp<64; fp++) acc += feat[256+5*fp+c]*W[fp*64+f];
    }
    float* dst = isSc ? sc_packed : g_packed;
    dst[(size_t)n*576 + p] = acc*inv_f;
  }
}

// ---------------- node linears as tiled GEMM (n_species==1 fast path) ----------------
__global__ __launch_bounds__(256) void node_gemm_kernel(
  const float* __restrict__ node_feats,
  const float* __restrict__ Wsc0, const float* __restrict__ Wsc1, const float* __restrict__ Wsc2,
  const float* __restrict__ Wu0,  const float* __restrict__ Wu1,  const float* __restrict__ Wu2,
  float* __restrict__ g_packed, float* __restrict__ sc_packed, int N)
{
  __shared__ float As[64][17];
  __shared__ float Bs[16][64];
  int tid = threadIdx.x;
  int tx = tid & 15, ty = tid >> 4;
  int s = blockIdx.y;
  int n0 = blockIdx.x*64;

  int sub = s % 9;
  int isSc = (s >= 9);
  int abase, astride;
  const float* W;
  if (sub == 0){ abase = 0; astride = 1; W = isSc? Wsc0 : Wu0; }
  else if (sub < 4){ int c = sub-1; abase = 64+c; astride = 3; W = isSc? Wsc1 : Wu1; }
  else { int c = sub-4; abase = 256+c; astride = 5; W = isSc? Wsc2 : Wu2; }
  int obase, ostride;
  if (isSc){ obase = abase; ostride = astride; }
  else {
    if (sub==0){ obase=0; ostride=1; }
    else if (sub<4){ obase = 64+64*(sub-1); ostride=1; }
    else { obase = 256+64*(sub-4); ostride=1; }
  }
  float* dst = isSc ? sc_packed : g_packed;

  float acc[4][4];
  #pragma unroll
  for(int i=0;i<4;i++)
    #pragma unroll
    for(int j=0;j<4;j++) acc[i][j]=0.f;

  for (int k0=0; k0<64; k0+=16){
    #pragma unroll
    for (int l=0;l<4;l++){
      int idx = tid + l*256;
      int row = idx>>4, kk = idx&15;
      int n = n0+row;
      As[row][kk] = (n<N)? node_feats[(size_t)n*576 + abase + astride*(k0+kk)] : 0.f;
    }
    #pragma unroll
    for (int l=0;l<4;l++){
      int idx = tid + l*256;
      int kk = idx>>6, j = idx&63;
      Bs[kk][j] = W[(k0+kk)*64 + j];
    }
    __syncthreads();
    #pragma unroll
    for (int kk=0; kk<16; kk++){
      float av[4];
      #pragma unroll
      for(int i=0;i<4;i++) av[i] = As[ty*4+i][kk];
      float4 bv = *(const float4*)&Bs[kk][tx*4];
      #pragma unroll
      for(int i=0;i<4;i++){
        acc[i][0] += av[i]*bv.x; acc[i][1] += av[i]*bv.y;
        acc[i][2] += av[i]*bv.z; acc[i][3] += av[i]*bv.w;
      }
    }
    __syncthreads();
  }
  const float scale = 0.125f;  // 1/sqrt(64)
  #pragma unroll
  for(int i=0;i<4;i++){
    int n = n0 + ty*4+i;
    if (n>=N) continue;
    #pragma unroll
    for(int j=0;j<4;j++){
      int f = tx*4+j;
      dst[(size_t)n*576 + obase + ostride*f] = acc[i][j]*scale;
    }
  }
}

// ---------------- CSR build ----------------
__global__ void count_kernel(const int* __restrict__ recv, int* __restrict__ counts, int E){
  int e = blockIdx.x*256 + threadIdx.x;
  if(e<E) atomicAdd(&counts[recv[e]],1);
}

__global__ __launch_bounds__(1024) void scan_kernel(const int* __restrict__ counts,
                                                    int* __restrict__ offsets,
                                                    int* __restrict__ cursor, int n){
  __shared__ int tmp[1024];
  int tid = threadIdx.x;
  int per = (n + 1023)/1024;
  int base = tid*per;
  int s = 0;
  for(int i=0;i<per;i++){ int idx=base+i; if(idx<n) s += counts[idx]; }
  tmp[tid]=s; __syncthreads();
  for(int off=1; off<1024; off<<=1){
    int v = (tid>=off)? tmp[tid-off] : 0;
    __syncthreads();
    tmp[tid]+=v;
    __syncthreads();
  }
  int run = (tid==0)? 0 : tmp[tid-1];
  for(int i=0;i<per;i++){
    int idx=base+i;
    if(idx<n){ offsets[idx]=run; cursor[idx]=run; run += counts[idx]; }
  }
  if(tid==1023) offsets[n]=tmp[1023];
}

__global__ void scatter_kernel(const int* __restrict__ recv, int* __restrict__ cursor,
                               int* __restrict__ edge_list, int E){
  int e = blockIdx.x*256 + threadIdx.x;
  if(e<E){ int pos=atomicAdd(&cursor[recv[e]],1); edge_list[pos]=e; }
}

// ---------------- fused geometry + radial MLP per edge (pos-indexed) ----------------
__global__ __launch_bounds__(256) void geomh_kernel(
  const float* __restrict__ vectors, const int* __restrict__ edge_list,
  const int* __restrict__ senders,
  const float* __restrict__ Wm1, const float* __restrict__ Wm2,
  float* __restrict__ shbuf, float* __restrict__ h2buf, int* __restrict__ spos, int E)
{
  int pos = blockIdx.x*256 + threadIdx.x;
  bool valid = pos < E;
  int pp = valid ? pos : (E-1);
  int e = edge_list[pp];
  if (valid) spos[pos] = senders[e];
  float vx=vectors[e*3], vy=vectors[e*3+1], vz=vectors[e*3+2];
  float x2 = vx*vx+vy*vy+vz*vz;
  float x  = sqrtf(fmaxf(x2, 1e-12f));
  float inv= 1.f/x;
  float ux=vx*inv, uy=vy*inv, uz=vz*inv;
  float env = 0.f;
  if(x<1.f){
    float x3=x*x*x; float x6=x3*x3; float x7=x6*x; float x8=x7*x;
    env = 1.f-28.f*x6+48.f*x7-21.f*x8;
  }
  float rad[8];
  #pragma unroll
  for(int nn=1;nn<=8;nn++)
    rad[nn-1] = 1.4142135623730951f * sinf(3.14159265358979323846f*(float)nn*x)*inv*env;
  {
    float sh[16];
    const float s3=1.7320508075688772f;
    sh[0]=s3*uy; sh[1]=s3*uz; sh[2]=s3*ux;
    const float s15=3.872983346207417f, s5=2.23606797749979f;
    sh[3]=s15*ux*uy; sh[4]=s15*uy*uz;
    sh[5]=0.5f*s5*(3.f*uz*uz-1.f);
    sh[6]=s15*ux*uz; sh[7]=0.5f*s15*(ux*ux-uy*uy);
    const float c35=2.091650066335189f, c105=10.246950765959598f;
    const float c21=1.620185174601965f, c7=1.3228756555322954f;
    sh[8] =c35*uy*(3.f*ux*ux-uy*uy);
    sh[9] =c105*ux*uy*uz;
    sh[10]=c21*uy*(5.f*uz*uz-1.f);
    sh[11]=c7*uz*(5.f*uz*uz-3.f);
    sh[12]=c21*ux*(5.f*uz*uz-1.f);
    sh[13]=0.5f*c105*uz*(ux*ux-uy*uy);
    sh[14]=c35*ux*(ux*ux-3.f*uy*uy);
    sh[15]=0.f;
    if (valid){
      float* sb = shbuf + (size_t)pos*16;
      #pragma unroll
      for(int k=0;k<16;k++) sb[k]=sh[k];
    }
  }
  float h2a[64];
  #pragma unroll
  for(int j=0;j<64;j++) h2a[j]=0.f;
  for(int i=0;i<64;i++){
    float a=0.f;
    #pragma unroll
    for(int r=0;r<8;r++) a += rad[r]*Wm1[r*64+i];
    a *= 0.3535533905932738f;           // 1/sqrt(8)
    float h1 = a/(1.f+expf(-a));
    const float* wrow = Wm2 + i*64;
    #pragma unroll
    for(int j=0;j<64;j++) h2a[j] += h1*wrow[j];
  }
  if (valid){
    #pragma unroll
    for(int j=0;j<64;j++){
      float b = h2a[j]*0.125f;          // 1/sqrt(64)
      h2buf[(size_t)j*E + pos] = b/(1.f+expf(-b));
    }
  }
}

// ---------------- mix = h2 @ Wm3 /8  (128x64 tiles, 8x4/thread, fp32 row-major out) ----------------
__global__ __launch_bounds__(256) void mix_gemm_kernel(
  const float* __restrict__ h2buf, const float* __restrict__ Wm3,
  float* __restrict__ mixbuf, int posLo, int cnt, int E)
{
  __shared__ float As[128][17];
  __shared__ float Bs[16][64];
  int tid=threadIdx.x; int tx=tid&15, ty=tid>>4;
  int r0 = blockIdx.x*128;
  int c0 = blockIdx.y*64;          // column tile over 832 (13 tiles)
  float acc[8][4];
  #pragma unroll
  for(int i=0;i<8;i++)
    #pragma unroll
    for(int j=0;j<4;j++) acc[i][j]=0.f;
  for(int k0=0;k0<64;k0+=16){
    #pragma unroll
    for(int l=0;l<8;l++){
      int idx=tid+l*256; int kk=idx>>7, row=idx&127;
      int r=r0+row;
      As[row][kk] = (r<cnt)? h2buf[(size_t)(k0+kk)*E + posLo + r] : 0.f;
    }
    #pragma unroll
    for(int l=0;l<4;l++){
      int idx=tid+l*256; int kk=idx>>6, j=idx&63;
      Bs[kk][j] = Wm3[(size_t)(k0+kk)*832 + c0 + j];
    }
    __syncthreads();
    #pragma unroll
    for(int kk=0;kk<16;kk++){
      float av[8];
      #pragma unroll
      for(int i=0;i<8;i++) av[i]=As[ty*8+i][kk];
      float4 bv = *(const float4*)&Bs[kk][tx*4];
      #pragma unroll
      for(int i=0;i<8;i++){
        acc[i][0]+=av[i]*bv.x; acc[i][1]+=av[i]*bv.y;
        acc[i][2]+=av[i]*bv.z; acc[i][3]+=av[i]*bv.w;
      }
    }
    __syncthreads();
  }
  #pragma unroll
  for(int i=0;i<8;i++){
    int r=r0+ty*8+i;
    if(r>=cnt) continue;
    float4 o;
    o.x=acc[i][0]*0.125f; o.y=acc[i][1]*0.125f;
    o.z=acc[i][2]*0.125f; o.w=acc[i][3]*0.125f;
    *(float4*)&mixbuf[(size_t)r*832 + c0 + tx*4] = o;
  }
}

// ---------------- fused message + segment-sum: one 256-thread block per node, 2 edges/wave/iter ----------------
// a_packed row (2752): [0,192) m0 ; [192,1152) m1 c*320+part*64+f ; [1152,2752) m2 c*320+part*64+f
__global__ __launch_bounds__(256) void node_accum_kernel(
  const float* __restrict__ g_packed, const int* __restrict__ spos,
  const float* __restrict__ shbuf, const float* __restrict__ cgbuf,
  const float* __restrict__ mixbuf, const int* __restrict__ offsets,
  float* __restrict__ a_packed, int posLo, int posHi, int N)
{
  __shared__ float accs[2752];
  __shared__ float cgs[504];
  __shared__ float sh_l[4][32];
  __shared__ float wt_l[4][208];
  int n = blockIdx.x; if (n>=N) return;
  int tid = threadIdx.x, wave = tid>>6, lane = tid&63;
  int e0 = offsets[n], e1 = offsets[n+1];
  int a0 = e0>posLo? e0:posLo;
  int a1 = e1<posHi? e1:posHi;
  bool first = (posLo==0);
  if (!first && a0>=a1) return;

  for (int i=tid;i<2752;i+=256) accs[i]=0.f;
  for (int i=tid;i<504;i+=256) cgs[i]=cgbuf[i];
  __syncthreads();

  float racc[43];
  #pragma unroll
  for(int k=0;k<43;k++) racc[k]=0.f;

  for (int base=a0+wave*2; base<a1; base+=8){
    int p0 = base;
    int p1 = base+1;
    bool v1 = (p1 < a1);
    int p1c = v1 ? p1 : p0;
    // stage sh for both edges (wave-local, in-order within wave)
    if (lane<16) sh_l[wave][lane] = shbuf[(size_t)p0*16 + lane];
    else if (lane<32) sh_l[wave][lane] = shbuf[(size_t)p1c*16 + (lane-16)];
    const float* sh0 = sh_l[wave];
    const float* sh1 = sh_l[wave]+16;
    wt_l[wave][lane] = w_entry(lane, sh0, cgs);
    if (lane<40) wt_l[wave][64+lane] = w_entry(64+lane, sh0, cgs);
    wt_l[wave][104+lane] = w_entry(lane, sh1, cgs);
    if (lane<40) wt_l[wave][168+lane] = w_entry(64+lane, sh1, cgs);
    const float* W0 = wt_l[wave];
    const float* W1 = wt_l[wave]+104;
    const float* gA = g_packed + (size_t)spos[p0]*576;
    const float* gB = g_packed + (size_t)spos[p1c]*576;
    const float* mxA = mixbuf + (size_t)(p0-posLo)*832;
    const float* mxB = mixbuf + (size_t)(p1c-posLo)*832;
    float z1 = v1 ? 1.f : 0.f;
    edge_accum(racc, gA, W0, sh0, mxA, 1.f, lane);
    edge_accum(racc, gB, W1, sh1, mxB, z1, lane);
  }
  __syncthreads();
  // cross-wave merge (4 phases)
  for (int w=0; w<4; w++){
    if (wave==w){
      accs[lane]     += racc[0];
      accs[64+lane]  += racc[1];
      accs[128+lane] += racc[2];
      #pragma unroll
      for(int c=0;c<3;c++)
        #pragma unroll
        for(int p=0;p<5;p++)
          accs[192+c*320+p*64+lane] += racc[3+c*5+p];
      #pragma unroll
      for(int c=0;c<5;c++)
        #pragma unroll
        for(int p=0;p<5;p++)
          accs[1152+c*320+p*64+lane] += racc[18+c*5+p];
    }
    __syncthreads();
  }
  if (first){
    for (int i=tid;i<2752;i+=256) a_packed[(size_t)n*2752+i] = accs[i];
  } else {
    for (int i=tid;i<2752;i+=256) a_packed[(size_t)n*2752+i] += accs[i];
  }
}

// ---------------- output GEMM into dbuf (704/node, comp-major d1/d2), 32-row tiles ----------------
__global__ __launch_bounds__(256) void out_gemm_kernel(
  const float* __restrict__ A, const float* __restrict__ Wd0,
  const float* __restrict__ Wd1, const float* __restrict__ Wd2,
  float* __restrict__ dbuf, int N)
{
  __shared__ float As[32][17];
  __shared__ float Bs[16][64];
  int tid = threadIdx.x;
  int tx = tid & 15, ty = tid >> 4;
  int s = blockIdx.y;
  int n0 = blockIdx.x*32;

  int abase, K, obase, bcol0, bstride;
  const float* W;
  float scale;
  if (s < 3){
    abase = 0; K = 192; W = Wd0; bcol0 = 64*s; bstride = 192;
    obase = 64*s;
    scale = 0.02282177322938192f;      // 1/sqrt(10*192)
  } else if (s < 6){
    int c = s-3;
    abase = 192+320*c; K = 320; W = Wd1; bcol0 = 0; bstride = 64;
    obase = 192+64*c;
    scale = 0.017677669529663688f;     // 1/sqrt(10*320)
  } else {
    int c = s-6;
    abase = 1152+320*c; K = 320; W = Wd2; bcol0 = 0; bstride = 64;
    obase = 384+64*c;
    scale = 0.017677669529663688f;
  }

  float acc[2][4];
  #pragma unroll
  for(int i=0;i<2;i++)
    #pragma unroll
    for(int j=0;j<4;j++) acc[i][j]=0.f;

  for (int k0=0; k0<K; k0+=16){
    #pragma unroll
    for (int l=0;l<2;l++){
      int idx = tid + l*256;
      int row = idx>>4, kk = idx&15;
      int n = n0+row;
      As[row][kk] = (n<N)? A[(size_t)n*2752 + abase + k0+kk] : 0.f;
    }
    #pragma unroll
    for (int l=0;l<4;l++){
      int idx = tid + l*256;
      int kk = idx>>6, j = idx&63;
      Bs[kk][j] = W[(size_t)(k0+kk)*bstride + bcol0 + j];
    }
    __syncthreads();
    #pragma unroll
    for (int kk=0; kk<16; kk++){
      float av[2];
      av[0] = As[ty*2][kk]; av[1] = As[ty*2+1][kk];
      float4 bv = *(const float4*)&Bs[kk][tx*4];
      #pragma unroll
      for(int i=0;i<2;i++){
        acc[i][0] += av[i]*bv.x; acc[i][1] += av[i]*bv.y;
        acc[i][2] += av[i]*bv.z; acc[i][3] += av[i]*bv.w;
      }
    }
    __syncthreads();
  }
  #pragma unroll
  for(int i=0;i<2;i++){
    int n = n0 + ty*2+i;
    if (n>=N) continue;
    #pragma unroll
    for(int j=0;j<4;j++){
      int col = tx*4+j;
      dbuf[(size_t)n*704 + obase + col] = acc[i][j]*scale;
    }
  }
}

// ---------------- epilogue: swish/gates + self connection ----------------
__global__ __launch_bounds__(256) void epilogue_kernel(
  const float* __restrict__ dbuf, const float* __restrict__ sc_packed,
  float* __restrict__ out, int N)
{
  int n = blockIdx.x; if(n>=N) return;
  const float* d = dbuf + (size_t)n*704;
  const float* sc = sc_packed + (size_t)n*576;
  float* o = out + (size_t)n*576;
  for (int p=threadIdx.x; p<576; p+=256){
    float v;
    if (p<64){
      float x = d[p];
      v = x/(1.f+expf(-x)) + sc[p];
    } else if (p<256){
      int r = p-64; int f = r/3, c = r-3*f;
      float g = d[64+f]; g = g/(1.f+expf(-g));
      v = d[192+64*c+f]*g + sc[p];
    } else {
      int r = p-256; int f = r/5, c = r-5*f;
      float g = d[128+f]; g = g/(1.f+expf(-g));
      v = d[384+64*c+f]*g + sc[p];
    }
    o[p] = v;
  }
}

// ---------------- host ----------------
extern "C" void kernel_launch(void* const* d_in, const int* in_sizes, int n_in,
                              void* d_out, int out_size, void* d_ws, size_t ws_size,
                              hipStream_t stream)
{
  const float* vectors    =(const float*)d_in[0];
  const float* node_feats =(const float*)d_in[1];
  const int*   node_specie=(const int*)  d_in[2];
  const int*   senders    =(const int*)  d_in[3];
  const int*   receivers  =(const int*)  d_in[4];
  const float* Wsc0=(const float*)d_in[5];
  const float* Wsc1=(const float*)d_in[6];
  const float* Wsc2=(const float*)d_in[7];
  const float* Wu0 =(const float*)d_in[8];
  const float* Wu1 =(const float*)d_in[9];
  const float* Wu2 =(const float*)d_in[10];
  const float* Wm1 =(const float*)d_in[11];
  const float* Wm2 =(const float*)d_in[12];
  const float* Wm3 =(const float*)d_in[13];
  const float* Wd0 =(const float*)d_in[14];
  const float* Wd1 =(const float*)d_in[15];
  const float* Wd2 =(const float*)d_in[16];
  float* out = (float*)d_out;

  int E = in_sizes[0]/3;
  int N = in_sizes[1]/576;
  int nspec = in_sizes[5]/4096;

  // workspace carve
  float* cgbuf     = (float*)d_ws;                         // 512
  float* g_packed  = cgbuf + 512;                          // N*576
  float* sc_packed = g_packed  + (size_t)N*576;            // N*576
  float* a_packed  = sc_packed + (size_t)N*576;            // N*2752
  float* shbuf     = a_packed + (size_t)N*2752;            // E*16
  float* h2buf     = shbuf + (size_t)E*16;                 // E*64 (transposed [64][E])
  int*   counts    = (int*)(h2buf + (size_t)E*64);         // N
  int*   offsets   = counts + N;                           // N+1
  int*   cursor    = offsets + (N+1);                      // N
  int*   edge_list = cursor + N;                           // E
  int*   spos      = edge_list + E;                        // E
  size_t used_bytes = (size_t)((char*)(spos + E) - (char*)d_ws);
  used_bytes = (used_bytes + 255) & ~(size_t)255;
  size_t avail = (ws_size > used_bytes) ? (ws_size - used_bytes) : 0;
  long long cap = (long long)(avail / (832u*4u));
  if (cap > E) cap = ((long long)E + 7) & ~7ll;     // as many edges per round as fit
  cap = (cap/8)*8;
  if (cap < 8) cap = 8;
  float* mixbuf = (float*)((char*)d_ws + used_bytes);      // cap*832 (row-major fp32)
  float* dbuf   = mixbuf;                                  // reuse after rounds: N*704

  hipMemsetAsync(counts, 0, (size_t)N*sizeof(int), stream);
  cg_init_kernel<<<2,256,0,stream>>>(cgbuf);
  if (nspec == 1){
    dim3 grid((N+63)/64, 18);
    node_gemm_kernel<<<grid,256,0,stream>>>(node_feats,Wsc0,Wsc1,Wsc2,Wu0,Wu1,Wu2,
                                            g_packed,sc_packed,N);
  } else {
    node_linear_kernel<<<N,256,0,stream>>>(node_feats,node_specie,Wsc0,Wsc1,Wsc2,Wu0,Wu1,Wu2,
                                           g_packed,sc_packed,N);
  }
  count_kernel<<<(E+255)/256,256,0,stream>>>(receivers,counts,E);
  scan_kernel<<<1,1024,0,stream>>>(counts,offsets,cursor,N);
  scatter_kernel<<<(E+255)/256,256,0,stream>>>(receivers,cursor,edge_list,E);
  geomh_kernel<<<(E+255)/256,256,0,stream>>>(vectors,edge_list,senders,Wm1,Wm2,
                                             shbuf,h2buf,spos,E);

  for (long long lo=0; lo<E; lo+=cap){
    long long hi = lo + cap; if (hi > E) hi = E;
    int cnt = (int)(hi - lo);
    {
      dim3 grid((cnt+127)/128, 13);
      mix_gemm_kernel<<<grid,256,0,stream>>>(h2buf,Wm3,mixbuf,(int)lo,cnt,E);
    }
    node_accum_kernel<<<N,256,0,stream>>>(g_packed,spos,shbuf,cgbuf,mixbuf,offsets,
                                          a_packed,(int)lo,(int)hi,N);
  }

  {
    dim3 grid((N+31)/32, 11);
    out_gemm_kernel<<<grid,256,0,stream>>>(a_packed,Wd0,Wd1,Wd2,dbuf,N);
  }
  epilogue_kernel<<<N,256,0,stream>>>(dbuf,sc_packed,out,N);
}